// Round 2
// baseline (7193.357 us; speedup 1.0000x reference)
//
#include <hip/hip_runtime.h>
#include <hip/hip_bf16.h>

typedef __hip_bfloat16 BF;
typedef unsigned short ushort_t;

#define B_N 8
#define L_N 4096

__device__ __forceinline__ float b2f(BF v){ return __bfloat162float(v); }
__device__ __forceinline__ BF f2b(float v){ return __float2bfloat16(v); }
__device__ __forceinline__ float siluf(float x){ return x / (1.0f + __expf(-x)); }

// -------- dtype detector: count bf16-NaN/Inf exponent patterns ----------
__global__ __launch_bounds__(256) void k_detect(const ushort_t* __restrict__ x,
                                                int* __restrict__ flag)
{
    __shared__ int cnt[256];
    int t = threadIdx.x;
    int c = 0;
    for (int i = t; i < 65536; i += 256) {
        ushort_t v = x[i];
        if (((v >> 7) & 0xFF) == 0xFF) c++;   // bf16 exponent all-ones => NaN/Inf
    }
    cnt[t] = c;
    __syncthreads();
    for (int s = 128; s > 0; s >>= 1) {
        if (t < s) cnt[t] += cnt[t + s];
        __syncthreads();
    }
    if (t == 0) flag[0] = (cnt[0] > 4) ? 1 : 0;  // 1 => source data is fp32
}

// -------- normalize any float input into clean bf16 ---------------------
__global__ __launch_bounds__(256) void k_convert(const void* __restrict__ src,
                                                 BF* __restrict__ dst, int n,
                                                 const int* __restrict__ flag)
{
    int fp32 = flag[0];
    int i = blockIdx.x * 256 + threadIdx.x;
    int stride = gridDim.x * 256;
    if (fp32) {
        const float* s = (const float*)src;
        for (; i < n; i += stride) {
            float v = s[i];
            unsigned u = __float_as_uint(v);
            if ((u & 0x7F800000u) == 0x7F800000u) v = 0.f;  // scrub NaN/Inf
            dst[i] = f2b(v);
        }
    } else {
        const ushort_t* s = (const ushort_t*)src;
        ushort_t* d = (ushort_t*)dst;
        for (; i < n; i += stride) {
            ushort_t v = s[i];
            if (((v >> 7) & 0xFF) == 0xFF) v = 0;           // scrub NaN/Inf
            d[i] = v;
        }
    }
}

// ---------------- weight transpose: out[c][r] = in[r][c] ----------------
__global__ __launch_bounds__(256) void k_transpose(const BF* __restrict__ in,
                                                   BF* __restrict__ out,
                                                   int rows, int cols)
{
    __shared__ BF tile[32][33];
    int c0 = blockIdx.x * 32, r0 = blockIdx.y * 32;
    int tx = threadIdx.x & 31, ty = threadIdx.x >> 5;
#pragma unroll
    for (int i = 0; i < 4; i++) {
        int r = r0 + ty + i * 8, c = c0 + tx;
        tile[ty + i * 8][tx] = (r < rows && c < cols) ? in[(long)r * cols + c] : f2b(0.f);
    }
    __syncthreads();
#pragma unroll
    for (int i = 0; i < 4; i++) {
        int c = c0 + ty + i * 8, r = r0 + tx;
        if (c < cols && r < rows) out[(long)c * rows + r] = tile[tx][ty + i * 8];
    }
}

// ---------------- 1x1 conv (Cout=512) + SiLU, channel-major -------------
// in: (B, cin, L) bf16; wt: [cin][512] bf16 (pre-transposed)
// final call: flag!=null -> write fp32 to outf when flag[0]==1
__global__ __launch_bounds__(256) void k_pw512(const BF* __restrict__ in, long in_bstride, int cin,
                                               const BF* __restrict__ wt,
                                               BF* __restrict__ outb, float* __restrict__ outf,
                                               long out_bstride, const int* __restrict__ flag)
{
    __shared__ float lds[128][32];
    int b = blockIdx.y;
    int l0 = blockIdx.x * 32;
    int t = threadIdx.x;
    const BF* A = in + (long)b * in_bstride + l0;
    float acc0[32], acc1[32];
#pragma unroll
    for (int r = 0; r < 32; r++) { acc0[r] = 0.f; acc1[r] = 0.f; }
    for (int c0 = 0; c0 < cin; c0 += 128) {
        __syncthreads();
#pragma unroll
        for (int i = 0; i < 16; i++) {
            int idx = t + i * 256;
            int c = idx >> 5, ll = idx & 31;
            lds[c][ll] = b2f(A[(long)(c0 + c) * L_N + ll]);
        }
        __syncthreads();
        const BF* wp = wt + (long)c0 * 512 + t;
        for (int c = 0; c < 128; c++) {
            float w0 = b2f(wp[0]);
            float w1 = b2f(wp[256]);
            wp += 512;
            const float4* row = (const float4*)(&lds[c][0]);
#pragma unroll
            for (int q = 0; q < 8; q++) {
                float4 a = row[q];
                acc0[4*q+0] += a.x * w0;  acc1[4*q+0] += a.x * w1;
                acc0[4*q+1] += a.y * w0;  acc1[4*q+1] += a.y * w1;
                acc0[4*q+2] += a.z * w0;  acc1[4*q+2] += a.z * w1;
                acc0[4*q+3] += a.w * w0;  acc1[4*q+3] += a.w * w1;
            }
        }
    }
    int wf = flag ? flag[0] : 0;
    if (wf) {
        float* O = outf + (long)b * out_bstride + l0;
#pragma unroll
        for (int r = 0; r < 32; r++) O[(long)t * L_N + r] = siluf(acc0[r]);
#pragma unroll
        for (int r = 0; r < 32; r++) O[(long)(t + 256) * L_N + r] = siluf(acc1[r]);
    } else {
        BF* O = outb + (long)b * out_bstride + l0;
#pragma unroll
        for (int r = 0; r < 32; r++) O[(long)t * L_N + r] = f2b(siluf(acc0[r]));
#pragma unroll
        for (int r = 0; r < 32; r++) O[(long)(t + 256) * L_N + r] = f2b(siluf(acc1[r]));
    }
}

// ---------------- 3x3 conv (256->256, pad 1) + SiLU ---------------------
__global__ __launch_bounds__(256) void k_conv3(const BF* __restrict__ in, long in_bstride,
                                               const BF* __restrict__ w,  // [256][256][9]
                                               BF* __restrict__ out, long out_bstride)
{
    __shared__ float s_in[8][6][66];
    __shared__ float s_w[8][32][9];
    int b = blockIdx.z;
    int o0 = blockIdx.y * 32;
    int y0 = blockIdx.x * 4;
    int t = threadIdx.x;
    int o = t & 31;
    int pg = t >> 5;
    int gx0 = pg * 8;
    const BF* Ab = in + (long)b * in_bstride;
    float acc[32];
#pragma unroll
    for (int i = 0; i < 32; i++) acc[i] = 0.f;
    for (int c0 = 0; c0 < 256; c0 += 8) {
        __syncthreads();
        for (int i = t; i < 8 * 6 * 66; i += 256) {
            int cc = i / 396; int rem = i - cc * 396;
            int row = rem / 66; int col = rem - row * 66;
            int gy = y0 - 1 + row; int gxx = col - 1;
            float v = 0.f;
            if (gy >= 0 && gy < 64 && gxx >= 0 && gxx < 64)
                v = b2f(Ab[(long)(c0 + cc) * L_N + gy * 64 + gxx]);
            s_in[cc][row][col] = v;
        }
        for (int i = t; i < 8 * 32 * 9; i += 256) {
            int oo = i / 72; int rem = i - oo * 72;
            int cc = rem / 9; int tap = rem - cc * 9;
            s_w[cc][oo][tap] = b2f(w[((long)(o0 + oo) * 256 + (c0 + cc)) * 9 + tap]);
        }
        __syncthreads();
#pragma unroll
        for (int cc = 0; cc < 8; cc++) {
            float wr[9];
#pragma unroll
            for (int k = 0; k < 9; k++) wr[k] = s_w[cc][o][k];
#pragma unroll
            for (int rr = 0; rr < 4; rr++) {
#pragma unroll
                for (int dy = 0; dy < 3; dy++) {
                    float v[10];
#pragma unroll
                    for (int j = 0; j < 10; j++) v[j] = s_in[cc][rr + dy][gx0 + j];
#pragma unroll
                    for (int i = 0; i < 8; i++) {
                        float s = acc[rr * 8 + i];
                        s += v[i + 0] * wr[dy * 3 + 0];
                        s += v[i + 1] * wr[dy * 3 + 1];
                        s += v[i + 2] * wr[dy * 3 + 2];
                        acc[rr * 8 + i] = s;
                    }
                }
            }
        }
    }
    BF* Ob = out + (long)b * out_bstride + (long)(o0 + o) * L_N;
#pragma unroll
    for (int rr = 0; rr < 4; rr++)
#pragma unroll
        for (int i = 0; i < 8; i++)
            Ob[(y0 + rr) * 64 + gx0 + i] = f2b(siluf(acc[rr * 8 + i]));
}

// ------- fused value/offset/attn-weight projections from q (=b2) --------
__global__ __launch_bounds__(256) void k_qkv(const BF* __restrict__ q, long q_bstride,
                                             const BF* __restrict__ vproj_w, const BF* __restrict__ vproj_b,
                                             const BF* __restrict__ off_w,  const BF* __restrict__ off_b,
                                             const BF* __restrict__ aw_w,   const BF* __restrict__ aw_b,
                                             BF* __restrict__ val, float* __restrict__ offb,
                                             float* __restrict__ awb)
{
    __shared__ float lds[256][32];
    int b = blockIdx.y, l0 = blockIdx.x * 32, t = threadIdx.x;
    const BF* A = q + (long)b * q_bstride + l0;
#pragma unroll
    for (int i = 0; i < 32; i++) {
        int idx = t + i * 256;
        int c = idx >> 5, ll = idx & 31;
        lds[c][ll] = b2f(A[(long)c * L_N + ll]);
    }
    __syncthreads();
    {
        float acc[32];
#pragma unroll
        for (int r = 0; r < 32; r++) acc[r] = 0.f;
        const BF* wp = vproj_w + t;
        for (int c = 0; c < 256; c++) {
            float w0 = b2f(wp[0]); wp += 256;
            const float4* row = (const float4*)(&lds[c][0]);
#pragma unroll
            for (int qq = 0; qq < 8; qq++) {
                float4 a = row[qq];
                acc[4*qq+0] += a.x * w0;
                acc[4*qq+1] += a.y * w0;
                acc[4*qq+2] += a.z * w0;
                acc[4*qq+3] += a.w * w0;
            }
        }
        float bias = b2f(vproj_b[t]);
        int h = t >> 5, d = t & 31;
        BF* vp = val + ((long)(b * 8 + h) * L_N) * 32 + d;
#pragma unroll
        for (int r = 0; r < 32; r++) vp[(long)(l0 + r) * 32] = f2b(acc[r] + bias);
    }
    if (t < 96) {
        float acc[32];
#pragma unroll
        for (int r = 0; r < 32; r++) acc[r] = 0.f;
        const BF* wp; int stride; float bias;
        if (t < 64) { wp = off_w + t;        stride = 64; bias = b2f(off_b[t]); }
        else        { wp = aw_w + (t - 64);  stride = 32; bias = b2f(aw_b[t - 64]); }
        for (int c = 0; c < 256; c++) {
            float w0 = b2f(wp[0]); wp += stride;
            const float4* row = (const float4*)(&lds[c][0]);
#pragma unroll
            for (int qq = 0; qq < 8; qq++) {
                float4 a = row[qq];
                acc[4*qq+0] += a.x * w0;
                acc[4*qq+1] += a.y * w0;
                acc[4*qq+2] += a.z * w0;
                acc[4*qq+3] += a.w * w0;
            }
        }
        if (t < 64) {
            float* op = offb + ((long)b * L_N + l0) * 64 + t;
#pragma unroll
            for (int r = 0; r < 32; r++) op[(long)r * 64] = acc[r] + bias;
        } else {
            float* ap = awb + ((long)b * L_N + l0) * 32 + (t - 64);
#pragma unroll
            for (int r = 0; r < 32; r++) ap[(long)r * 32] = acc[r] + bias;
        }
    }
}

// ---------------- deformable sampler ------------------------------------
__global__ __launch_bounds__(256) void k_samp(const BF* __restrict__ rb,
                                              const float* __restrict__ offb,
                                              const float* __restrict__ awb,
                                              const BF* __restrict__ val,
                                              BF* __restrict__ sout)
{
    int t = threadIdx.x;
    int g = blockIdx.x * 8 + (t >> 5);
    int d = t & 31;
    int l = g & (L_N - 1);
    int h = (g >> 12) & 7;
    int b = g >> 15;
    const float* op = offb + ((long)b * L_N + l) * 64 + h * 8;
    const float* ap = awb + ((long)b * L_N + l) * 32 + h * 4;
    float rx = b2f(rb[((long)b * L_N + l) * 2 + 0]);
    float ry = b2f(rb[((long)b * L_N + l) * 2 + 1]);
    float lg0 = ap[0], lg1 = ap[1], lg2 = ap[2], lg3 = ap[3];
    float m = fmaxf(fmaxf(lg0, lg1), fmaxf(lg2, lg3));
    float e[4];
    e[0] = __expf(lg0 - m); e[1] = __expf(lg1 - m);
    e[2] = __expf(lg2 - m); e[3] = __expf(lg3 - m);
    float inv = 1.f / (e[0] + e[1] + e[2] + e[3]);
    const BF* vb = val + ((long)(b * 8 + h) * L_N) * 32 + d;
    float o = 0.f;
#pragma unroll
    for (int p = 0; p < 4; p++) {
        float aw = e[p] * inv;
        float gx = rx * 64.f + op[p * 2 + 0] - 0.5f;
        float gy = ry * 64.f + op[p * 2 + 1] - 0.5f;
        float fx = floorf(gx), fy = floorf(gy);
        int x0 = (int)fx, yy0 = (int)fy;
        float wx1 = gx - fx, wy1 = gy - fy;
        float wx0 = 1.f - wx1, wy0 = 1.f - wy1;
        float c00 = 0.f, c10 = 0.f, c01 = 0.f, c11 = 0.f;
        if (x0 >= 0 && x0 < 64 && yy0 >= 0 && yy0 < 64)         c00 = b2f(vb[(long)(yy0 * 64 + x0) * 32]);
        if (x0+1 >= 0 && x0+1 < 64 && yy0 >= 0 && yy0 < 64)     c10 = b2f(vb[(long)(yy0 * 64 + x0 + 1) * 32]);
        if (x0 >= 0 && x0 < 64 && yy0+1 >= 0 && yy0+1 < 64)     c01 = b2f(vb[(long)((yy0 + 1) * 64 + x0) * 32]);
        if (x0+1 >= 0 && x0+1 < 64 && yy0+1 >= 0 && yy0+1 < 64) c11 = b2f(vb[(long)((yy0 + 1) * 64 + x0 + 1) * 32]);
        o += aw * (c00 * wx0 * wy0 + c10 * wx1 * wy0 + c01 * wx0 * wy1 + c11 * wx1 * wy1);
    }
    sout[((long)b * L_N + l) * 256 + h * 32 + d] = f2b(o);
}

// ---------------- output projection -> channel-major attn ---------------
__global__ __launch_bounds__(256) void k_outproj(const BF* __restrict__ sin,
                                                 const BF* __restrict__ w,
                                                 const BF* __restrict__ bias,
                                                 BF* __restrict__ out, long out_bstride)
{
    __shared__ float lds[256][36];
    int b = blockIdx.y, l0 = blockIdx.x * 32, t = threadIdx.x;
    const BF* A = sin + ((long)b * L_N + l0) * 256;
#pragma unroll
    for (int i = 0; i < 32; i++) {
        int idx = t + i * 256;
        int r = idx >> 8, c = idx & 255;
        lds[c][r] = b2f(A[(long)r * 256 + c]);
    }
    __syncthreads();
    float acc[32];
#pragma unroll
    for (int r = 0; r < 32; r++) acc[r] = 0.f;
    const BF* wp = w + t;
    for (int c = 0; c < 256; c++) {
        float wv = b2f(wp[0]); wp += 256;
        const float4* row = (const float4*)(&lds[c][0]);
#pragma unroll
        for (int q = 0; q < 8; q++) {
            float4 a = row[q];
            acc[4*q+0] += a.x * wv;
            acc[4*q+1] += a.y * wv;
            acc[4*q+2] += a.z * wv;
            acc[4*q+3] += a.w * wv;
        }
    }
    float bs = b2f(bias[t]);
    BF* O = out + (long)b * out_bstride + (long)t * L_N + l0;
#pragma unroll
    for (int r = 0; r < 32; r++) O[r] = f2b(acc[r] + bs);
}

extern "C" void kernel_launch(void* const* d_in, const int* in_sizes, int n_in,
                              void* d_out, int out_size, void* d_ws, size_t ws_size,
                              hipStream_t stream)
{
    (void)in_sizes; (void)n_in; (void)out_size; (void)ws_size;
    char* ws = (char*)d_ws;
    size_t woff = 0;
    auto carve = [&](size_t bytes) -> char* {
        char* p = ws + woff;
        woff += (bytes + 255) & ~(size_t)255;
        return p;
    };
    int* flag = (int*)carve(256);
    // converted-input arena (bf16)
    BF* rb_c    = (BF*)carve(65536 * 2);
    BF* cv1_c   = (BF*)carve(262144 * 2);
    BF* m0c1_c  = (BF*)carve(589824 * 2);
    BF* m0c2_c  = (BF*)carve(589824 * 2);
    BF* m1c1_c  = (BF*)carve(589824 * 2);
    BF* m1c2_c  = (BF*)carve(589824 * 2);
    BF* vpw_c   = (BF*)carve(65536 * 2);
    BF* vpb_c   = (BF*)carve(256 * 2);
    BF* ofw_c   = (BF*)carve(16384 * 2);
    BF* ofb_c   = (BF*)carve(64 * 2);
    BF* aww_c   = (BF*)carve(8192 * 2);
    BF* awbias_c= (BF*)carve(32 * 2);
    BF* outw_c  = (BF*)carve(65536 * 2);
    BF* outb_c  = (BF*)carve(256 * 2);
    BF* cv2_c   = (BF*)carve(655360 * 2);
    BF* cat  = (BF*)carve((size_t)B_N * 1280 * L_N * 2);   // [a|b|b1|b2|attn]
    BF* wt1  = (BF*)carve((size_t)512 * 512 * 2);
    BF* wt2  = (BF*)carve((size_t)1280 * 512 * 2);
    // UNION region: x_c overlaps tmp/val (disjoint lifetimes)
    char* U = carve((size_t)62914560);
    BF*    x_c  = (BF*)U;                                  // 33,554,432 B (dies after cv1)
    BF*    tmp  = (BF*)U;                                  // 16 MB (conv chain)
    BF*    val  = (BF*)(U + 16777216);                     // 16 MB (qkv->samp)
    float* offb = (float*)(U + 33554432);                  // 8 MB
    float* awb  = (float*)(U + 41943040);                  // 4 MB
    BF*    sout = (BF*)(U + 46137344);                     // 16 MB

    // 1) detect dtype from raw bits of x
    k_detect<<<1, 256, 0, stream>>>((const ushort_t*)d_in[0], flag);
    // 2) normalize all float inputs to bf16
    auto conv = [&](const void* src, BF* dst, int n) {
        int grid = (n + 16383) / 16384; if (grid < 1) grid = 1;
        k_convert<<<grid, 256, 0, stream>>>(src, dst, n, flag);
    };
    conv(d_in[0],  x_c,    16777216);
    conv(d_in[1],  rb_c,   65536);
    conv(d_in[3],  cv1_c,  262144);
    conv(d_in[4],  m0c1_c, 589824);
    conv(d_in[5],  m0c2_c, 589824);
    conv(d_in[6],  m1c1_c, 589824);
    conv(d_in[7],  m1c2_c, 589824);
    conv(d_in[8],  vpw_c,  65536);
    conv(d_in[9],  vpb_c,  256);
    conv(d_in[10], ofw_c,  16384);
    conv(d_in[11], ofb_c,  64);
    conv(d_in[12], aww_c,  8192);
    conv(d_in[13], awbias_c, 32);
    conv(d_in[14], outw_c, 65536);
    conv(d_in[15], outb_c, 256);
    conv(d_in[16], cv2_c,  655360);

    k_transpose<<<dim3(16, 16), 256, 0, stream>>>(cv1_c, wt1, 512, 512);
    k_transpose<<<dim3(40, 16), 256, 0, stream>>>(cv2_c, wt2, 512, 1280);
    // cv1: x -> cat ch 0..511  (x_c dies here; tmp/val area reused after)
    k_pw512<<<dim3(128, 8), 256, 0, stream>>>(x_c, (long)512 * L_N, 512, wt1,
                                              cat, nullptr, (long)1280 * L_N, nullptr);
    k_conv3<<<dim3(16, 8, 8), 256, 0, stream>>>(cat + (size_t)256 * L_N, (long)1280 * L_N, m0c1_c, tmp, (long)256 * L_N);
    k_conv3<<<dim3(16, 8, 8), 256, 0, stream>>>(tmp, (long)256 * L_N, m0c2_c, cat + (size_t)512 * L_N, (long)1280 * L_N);
    k_conv3<<<dim3(16, 8, 8), 256, 0, stream>>>(cat + (size_t)512 * L_N, (long)1280 * L_N, m1c1_c, tmp, (long)256 * L_N);
    k_conv3<<<dim3(16, 8, 8), 256, 0, stream>>>(tmp, (long)256 * L_N, m1c2_c, cat + (size_t)768 * L_N, (long)1280 * L_N);
    k_qkv<<<dim3(128, 8), 256, 0, stream>>>(cat + (size_t)768 * L_N, (long)1280 * L_N,
                                            vpw_c, vpb_c, ofw_c, ofb_c, aww_c, awbias_c,
                                            val, offb, awb);
    k_samp<<<dim3(32768), 256, 0, stream>>>(rb_c, offb, awb, val, sout);
    k_outproj<<<dim3(128, 8), 256, 0, stream>>>(sout, outw_c, outb_c, cat + (size_t)1024 * L_N, (long)1280 * L_N);
    // cv2: cat (1280 ch) -> out; dtype of the store follows the flag
    k_pw512<<<dim3(128, 8), 256, 0, stream>>>(cat, (long)1280 * L_N, 1280, wt2,
                                              (BF*)d_out, (float*)d_out, (long)512 * L_N, flag);
}

// Round 4
// 1025.198 us; speedup vs baseline: 7.0166x; 7.0166x over previous
//
#include <hip/hip_runtime.h>
#include <hip/hip_bf16.h>

typedef __hip_bfloat16 BF;
typedef unsigned short ushort_t;
typedef __attribute__((ext_vector_type(8))) short short8;
typedef __attribute__((ext_vector_type(4))) float f32x4;

#define B_N 8
#define L_N 4096

__device__ __forceinline__ float b2f(BF v){ return __bfloat162float(v); }
__device__ __forceinline__ BF f2b(float v){ return __float2bfloat16(v); }
__device__ __forceinline__ float siluf(float x){ return x / (1.0f + __expf(-x)); }

// load element idx from raw buffer that is fp32 (flagv=1) or bf16 (0); scrub NaN/Inf
__device__ __forceinline__ float load_raw(const void* src, long idx, int fp32)
{
    if (fp32) {
        float v = ((const float*)src)[idx];
        unsigned u = __float_as_uint(v);
        if ((u & 0x7F800000u) == 0x7F800000u) v = 0.f;
        return v;
    } else {
        ushort_t v = ((const ushort_t*)src)[idx];
        if (((v >> 7) & 0xFF) == 0xFF) v = 0;
        unsigned u = ((unsigned)v) << 16;
        return __uint_as_float(u);
    }
}

// -------- dtype detector: count bf16-NaN/Inf exponent patterns ----------
__global__ __launch_bounds__(256) void k_detect(const ushort_t* __restrict__ x,
                                                int* __restrict__ flag)
{
    __shared__ int cnt[256];
    int t = threadIdx.x;
    int c = 0;
    for (int i = t; i < 65536; i += 256) {
        ushort_t v = x[i];
        if (((v >> 7) & 0xFF) == 0xFF) c++;
    }
    cnt[t] = c;
    __syncthreads();
    for (int s = 128; s > 0; s >>= 1) {
        if (t < s) cnt[t] += cnt[t + s];
        __syncthreads();
    }
    if (t == 0) flag[0] = (cnt[0] > 4) ? 1 : 0;  // 1 => source data is fp32
}

// -------- normalize a float input into clean bf16 -----------------------
__global__ __launch_bounds__(256) void k_convert(const void* __restrict__ src,
                                                 BF* __restrict__ dst, int n,
                                                 const int* __restrict__ flag)
{
    int fp32 = flag[0];
    int i = blockIdx.x * 256 + threadIdx.x;
    int stride = gridDim.x * 256;
    for (; i < n; i += stride) dst[i] = f2b(load_raw(src, i, fp32));
}

// -------- convert x (B,512,L) into cat ch512..1023 region per batch -----
__global__ __launch_bounds__(256) void k_convert_x(const void* __restrict__ src,
                                                   BF* __restrict__ cat,
                                                   const int* __restrict__ flag)
{
    int fp32 = flag[0];
    const long PB = (long)512 * L_N;          // 2,097,152 elems per batch
    const long CAT = (long)1280 * L_N;
    long i = (long)blockIdx.x * 256 + threadIdx.x;
    long stride = (long)gridDim.x * 256;
    for (; i < (long)B_N * PB; i += stride) {
        long b = i / PB, j = i - b * PB;
        cat[b * CAT + PB /*ch512 offset = 512*L_N*/ + j] = f2b(load_raw(src, i, fp32));
    }
}

// ---- zero-fill bf16 region ---------------------------------------------
__global__ __launch_bounds__(256) void k_zerobf(BF* __restrict__ p, int n)
{
    int i = blockIdx.x * 256 + threadIdx.x;
    if (i < n) p[i] = f2b(0.f);
}

// ---- matrix transpose+convert: raw in[r][c] -> out[(c+roff)*opitch + r]
__global__ __launch_bounds__(256) void k_tr_mat(const void* __restrict__ in,
                                                BF* __restrict__ out,
                                                int rows, int cols, int opitch, int roff,
                                                const int* __restrict__ flag)
{
    __shared__ BF tile[32][33];
    int fp32 = flag[0];
    int c0 = blockIdx.x * 32, r0 = blockIdx.y * 32;
    int tx = threadIdx.x & 31, ty = threadIdx.x >> 5;
#pragma unroll
    for (int i = 0; i < 4; i++) {
        int r = r0 + ty + i * 8, c = c0 + tx;
        tile[ty + i * 8][tx] = (r < rows && c < cols) ? f2b(load_raw(in, (long)r * cols + c, fp32))
                                                      : f2b(0.f);
    }
    __syncthreads();
#pragma unroll
    for (int i = 0; i < 4; i++) {
        int c = c0 + ty + i * 8, r = r0 + tx;
        if (c < cols && r < rows) out[(long)(c + roff) * opitch + r] = tile[tx][ty + i * 8];
    }
}

// ---- conv weight transpose+convert: raw w[oc][ic][9] -> wt[tap][oc][ic]
__global__ __launch_bounds__(256) void k_tr_w9(const void* __restrict__ w,
                                               BF* __restrict__ wt,
                                               const int* __restrict__ flag)
{
    int fp32 = flag[0];
    int idx = blockIdx.x * 256 + threadIdx.x;      // 65536 = oc*256+ic
    int oc = idx >> 8, ic = idx & 255;
#pragma unroll
    for (int tap = 0; tap < 9; tap++)
        wt[((long)tap * 256 + oc) * 256 + ic] = f2b(load_raw(w, (long)idx * 9 + tap, fp32));
}

// ================= universal MFMA implicit-GEMM conv ====================
// M-tile: 128 pixels (2 image rows).  Block = 256 thr (4 waves), wave tile
// M=128 x N=64 (8 m-frags x 4 n-frags).  K = cin * TAPS, chunked by 32 ic.
// LDS A: [px_row][ic] pitch 40 bf16 (80B, 16B-aligned b128 reads).
// TAPS==9: rows 0..255 = pixels px0-64 .. px0+191 (halo), row 256 = zeros.
// TAPS==1: rows 0..127 = pixels px0 .. px0+127.
// modes: 0 = silu->bf16 ch-major | 1 = silu-> bf16/fp32 by flag (cv2)
//        2 = qkv epilogue        | 3 = +bias, no act, bf16 ch-major
template<int TAPS, bool PXM>
__global__ __launch_bounds__(256, 2) void k_mconv(
    const BF* __restrict__ in, long in_bstride, int cin,
    const BF* __restrict__ wT, int ocp,
    const BF* __restrict__ bias, int coutp, int mode,
    BF* __restrict__ outb, float* __restrict__ outf, long out_bstride,
    const int* __restrict__ flag,
    BF* __restrict__ valp, float* __restrict__ offb, float* __restrict__ awb)
{
    constexpr int NROWS = (TAPS == 9) ? 257 : 128;
    __shared__ short ldsA[NROWS * 40];

    const int t    = threadIdx.x;
    const int lane = t & 63;
    const int wv   = t >> 6;
    const int ln   = lane & 15;
    const int kg   = lane >> 4;          // 0..3
    const int px0  = blockIdx.x * 128;
    const int b    = blockIdx.y;
    const int nbase = blockIdx.z * 256 + wv * 64;
    const bool active = (nbase < coutp);
    const BF* inb = in + (long)b * in_bstride;

    if (TAPS == 9) {                      // zero row 256 (visible after 1st barrier)
        if (t < 20) ((unsigned*)&ldsA[256 * 40])[t] = 0u;
    }

    f32x4 acc[8][4];
#pragma unroll
    for (int mf = 0; mf < 8; mf++)
#pragma unroll
        for (int nf = 0; nf < 4; nf++) {
            f32x4 z = {0.f, 0.f, 0.f, 0.f};
            acc[mf][nf] = z;
        }

    const int nchunks = cin >> 5;
    for (int c0i = 0; c0i < nchunks; ++c0i) {
        const int c0 = c0i << 5;
        __syncthreads();
        if (PXM) {
            // in[px][cin], ic contiguous: direct 16B copies
            int px = t >> 1, half = t & 1;
            const short* src = (const short*)(inb + (long)(px0 + px) * cin + c0 + half * 16);
            short8 v0 = *(const short8*)(src);
            short8 v1 = *(const short8*)(src + 8);
            *(short8*)&ldsA[px * 40 + half * 16]     = v0;
            *(short8*)&ldsA[px * 40 + half * 16 + 8] = v1;
        } else {
            // channel-major (cin, 4096): transpose-stage 32 ic x NR pixels
            constexpr int S = (TAPS == 9) ? 16 : 8;
            int icp = t & 15, seg = t >> 4;
            int gp0 = px0 + ((TAPS == 9) ? -64 : 0) + seg * S;
            bool v = (gp0 >= 0) && (gp0 < L_N);
            const BF* p0 = inb + (long)(c0 + icp * 2) * L_N + gp0;
            const BF* p1 = p0 + L_N;
#pragma unroll
            for (int jj = 0; jj < S; jj += 8) {
                short8 a0 = {0,0,0,0,0,0,0,0}, a1 = {0,0,0,0,0,0,0,0};
                if (v) { a0 = *(const short8*)(p0 + jj); a1 = *(const short8*)(p1 + jj); }
#pragma unroll
                for (int k = 0; k < 8; k++) {
                    unsigned pk = (unsigned)(ushort_t)a0[k] | ((unsigned)(ushort_t)a1[k] << 16);
                    *(unsigned*)&ldsA[(seg * S + jj + k) * 40 + icp * 2] = pk;
                }
            }
        }
        __syncthreads();
        if (active) {
#pragma unroll
            for (int tap = 0; tap < TAPS; ++tap) {
                const int dy = (TAPS == 9) ? (tap / 3 - 1) : 0;
                const int dx = (TAPS == 9) ? (tap % 3 - 1) : 0;
                short8 bfr[4];
#pragma unroll
                for (int nf = 0; nf < 4; nf++) {
                    int oc = nbase + nf * 16 + ln;
                    bfr[nf] = *(const short8*)(wT + ((long)(tap * ocp + oc) * cin + c0 + kg * 8));
                }
                short8 afr[8];
#pragma unroll
                for (int mf = 0; mf < 8; mf++) {
                    int ml = mf * 16 + ln;
                    int row;
                    if (TAPS == 9) {
                        int xs = (ml & 63) + dx;
                        row = (xs >= 0 && xs < 64) ? (ml + dy * 64 + dx + 64) : 256;
                    } else {
                        row = ml;
                    }
                    afr[mf] = *(const short8*)&ldsA[row * 40 + kg * 8];
                }
#pragma unroll
                for (int mf = 0; mf < 8; mf++)
#pragma unroll
                    for (int nf = 0; nf < 4; nf++)
                        acc[mf][nf] = __builtin_amdgcn_mfma_f32_16x16x32_bf16(
                            afr[mf], bfr[nf], acc[mf][nf], 0, 0, 0);
            }
        }
    }
    if (!active) return;

    // ---------------- epilogue ----------------
    const int wf = (mode == 1 && flag) ? flag[0] : 0;
#pragma unroll
    for (int mf = 0; mf < 8; mf++) {
        int px = px0 + mf * 16 + kg * 4;
#pragma unroll
        for (int nf = 0; nf < 4; nf++) {
            int oc = nbase + nf * 16 + ln;
            f32x4 a = acc[mf][nf];
            if (mode == 0 || mode == 1) {
                a.x = siluf(a.x); a.y = siluf(a.y); a.z = siluf(a.z); a.w = siluf(a.w);
                if (wf) {
                    float* dst = outf + (long)b * out_bstride + (long)oc * L_N + px;
                    *(f32x4*)dst = a;
                } else {
                    BF* dst = outb + (long)b * out_bstride + (long)oc * L_N + px;
                    dst[0] = f2b(a.x); dst[1] = f2b(a.y); dst[2] = f2b(a.z); dst[3] = f2b(a.w);
                }
            } else if (mode == 3) {
                float bs = b2f(bias[oc]);
                BF* dst = outb + (long)b * out_bstride + (long)oc * L_N + px;
                dst[0] = f2b(a.x + bs); dst[1] = f2b(a.y + bs);
                dst[2] = f2b(a.z + bs); dst[3] = f2b(a.w + bs);
            } else {  // mode 2: qkv
                if (oc >= 352) continue;
                float bs = b2f(bias[oc]);
                a.x += bs; a.y += bs; a.z += bs; a.w += bs;
                if (oc < 256) {
                    int h = oc >> 5, d = oc & 31;
                    BF* vp = valp + ((long)(b * 8 + h) * L_N + px) * 32 + d;
                    vp[0] = f2b(a.x); vp[32] = f2b(a.y); vp[64] = f2b(a.z); vp[96] = f2b(a.w);
                } else if (oc < 320) {
                    float* op = offb + ((long)b * L_N + px) * 64 + (oc - 256);
                    op[0] = a.x; op[64] = a.y; op[128] = a.z; op[192] = a.w;
                } else {
                    float* ap = awb + ((long)b * L_N + px) * 32 + (oc - 320);
                    ap[0] = a.x; ap[32] = a.y; ap[64] = a.z; ap[96] = a.w;
                }
            }
        }
    }
}

// ---------------- deformable sampler ------------------------------------
__global__ __launch_bounds__(256) void k_samp(const void* __restrict__ rb_raw,
                                              const int* __restrict__ flag,
                                              const float* __restrict__ offb,
                                              const float* __restrict__ awb,
                                              const BF* __restrict__ val,
                                              BF* __restrict__ sout)
{
    int fp32 = flag[0];
    int t = threadIdx.x;
    int g = blockIdx.x * 8 + (t >> 5);
    int d = t & 31;
    int l = g & (L_N - 1);
    int h = (g >> 12) & 7;
    int b = g >> 15;
    const float* op = offb + ((long)b * L_N + l) * 64 + h * 8;
    const float* ap = awb + ((long)b * L_N + l) * 32 + h * 4;
    float rx = load_raw(rb_raw, ((long)b * L_N + l) * 2 + 0, fp32);
    float ry = load_raw(rb_raw, ((long)b * L_N + l) * 2 + 1, fp32);
    float lg0 = ap[0], lg1 = ap[1], lg2 = ap[2], lg3 = ap[3];
    float m = fmaxf(fmaxf(lg0, lg1), fmaxf(lg2, lg3));
    float e[4];
    e[0] = __expf(lg0 - m); e[1] = __expf(lg1 - m);
    e[2] = __expf(lg2 - m); e[3] = __expf(lg3 - m);
    float inv = 1.f / (e[0] + e[1] + e[2] + e[3]);
    const BF* vb = val + ((long)(b * 8 + h) * L_N) * 32 + d;
    float o = 0.f;
#pragma unroll
    for (int p = 0; p < 4; p++) {
        float aw = e[p] * inv;
        float gx = rx * 64.f + op[p * 2 + 0] - 0.5f;
        float gy = ry * 64.f + op[p * 2 + 1] - 0.5f;
        float fx = floorf(gx), fy = floorf(gy);
        int x0 = (int)fx, yy0 = (int)fy;
        float wx1 = gx - fx, wy1 = gy - fy;
        float wx0 = 1.f - wx1, wy0 = 1.f - wy1;
        float c00 = 0.f, c10 = 0.f, c01 = 0.f, c11 = 0.f;
        if (x0 >= 0 && x0 < 64 && yy0 >= 0 && yy0 < 64)         c00 = b2f(vb[(long)(yy0 * 64 + x0) * 32]);
        if (x0+1 >= 0 && x0+1 < 64 && yy0 >= 0 && yy0 < 64)     c10 = b2f(vb[(long)(yy0 * 64 + x0 + 1) * 32]);
        if (x0 >= 0 && x0 < 64 && yy0+1 >= 0 && yy0+1 < 64)     c01 = b2f(vb[(long)((yy0 + 1) * 64 + x0) * 32]);
        if (x0+1 >= 0 && x0+1 < 64 && yy0+1 >= 0 && yy0+1 < 64) c11 = b2f(vb[(long)((yy0 + 1) * 64 + x0 + 1) * 32]);
        o += aw * (c00 * wx0 * wy0 + c10 * wx1 * wy0 + c01 * wx0 * wy1 + c11 * wx1 * wy1);
    }
    sout[((long)b * L_N + l) * 256 + h * 32 + d] = f2b(o);
}

extern "C" void kernel_launch(void* const* d_in, const int* in_sizes, int n_in,
                              void* d_out, int out_size, void* d_ws, size_t ws_size,
                              hipStream_t stream)
{
    (void)in_sizes; (void)n_in; (void)out_size; (void)ws_size;
    char* ws = (char*)d_ws;
    size_t woff = 0;
    auto carve = [&](size_t bytes) -> char* {
        char* p = ws + woff;
        woff += (bytes + 255) & ~(size_t)255;
        return p;
    };
    // total carve ~130.6 MB (round 2's ~153 MB footprint was proven safe)
    int* flag   = (int*)carve(256);
    BF* cv1_c   = (BF*)carve(262144 * 2);     // [512 oc][512 ic] = wT directly
    BF* cv2_c   = (BF*)carve(655360 * 2);     // [512 oc][1280 ic] = wT directly
    BF* qb      = (BF*)carve(384 * 2);        // vproj_b | off_b | aw_b
    BF* outb_c  = (BF*)carve(256 * 2);
    BF* wTq     = (BF*)carve((size_t)384 * 256 * 2);
    BF* wTo     = (BF*)carve((size_t)256 * 256 * 2);
    BF* wt9_0   = (BF*)carve(589824 * 2);
    BF* wt9_1   = (BF*)carve(589824 * 2);
    BF* wt9_2   = (BF*)carve(589824 * 2);
    BF* wt9_3   = (BF*)carve(589824 * 2);
    BF* cat     = (BF*)carve((size_t)B_N * 1280 * L_N * 2);   // [a|b|b1|b2|attn]
    // UNION region, 44 MB (disjoint lifetimes):
    //   tmp  U+0      (16MB)  conv chain scratch, dead after m1_cv2
    //   sout U+0      (16MB)  written by samp (after tmp dead), read by outproj
    //   val  U+16MB   (16MB)  qkv -> samp
    //   offb U+32MB   ( 8MB)  qkv -> samp
    //   awb  U+40MB   ( 4MB)  qkv -> samp
    char* U = carve((size_t)46137344);
    BF*    tmp  = (BF*)U;
    BF*    sout = (BF*)U;
    BF*    val  = (BF*)(U + 16777216);
    float* offb = (float*)(U + 33554432);
    float* awb  = (float*)(U + 41943040);

    k_detect<<<1, 256, 0, stream>>>((const ushort_t*)d_in[0], flag);
    // x -> cat ch 512..1023 region (per-batch scatter); read by cv1 only
    k_convert_x<<<1024, 256, 0, stream>>>(d_in[0], cat, flag);
    auto conv = [&](const void* src, BF* dst, int n) {
        int grid = (n + 16383) / 16384; if (grid < 1) grid = 1;
        k_convert<<<grid, 256, 0, stream>>>(src, dst, n, flag);
    };
    conv(d_in[3],  cv1_c,  262144);
    conv(d_in[16], cv2_c,  655360);
    conv(d_in[9],  qb,     256);
    conv(d_in[11], qb + 256, 64);
    conv(d_in[13], qb + 320, 32);
    conv(d_in[15], outb_c, 256);

    // weight transposes (+convert): [ic][oc] -> [oc][ic]
    k_tr_mat<<<dim3(8, 8), 256, 0, stream>>>(d_in[8],  wTq, 256, 256, 256, 0,   flag);
    k_tr_mat<<<dim3(2, 8), 256, 0, stream>>>(d_in[10], wTq, 256, 64,  256, 256, flag);
    k_tr_mat<<<dim3(1, 8), 256, 0, stream>>>(d_in[12], wTq, 256, 32,  256, 320, flag);
    k_zerobf<<<32, 256, 0, stream>>>(wTq + (size_t)352 * 256, 32 * 256);
    k_tr_mat<<<dim3(8, 8), 256, 0, stream>>>(d_in[14], wTo, 256, 256, 256, 0,   flag);
    k_tr_w9<<<256, 256, 0, stream>>>(d_in[4], wt9_0, flag);
    k_tr_w9<<<256, 256, 0, stream>>>(d_in[5], wt9_1, flag);
    k_tr_w9<<<256, 256, 0, stream>>>(d_in[6], wt9_2, flag);
    k_tr_w9<<<256, 256, 0, stream>>>(d_in[7], wt9_3, flag);

    const long CAT = (long)1280 * L_N, C1S = (long)512 * L_N, C0S = (long)256 * L_N;
    // cv1: x (cat ch 512..1023 view, 512ch) -> cat ch 0..511, silu
    k_mconv<1, false><<<dim3(32, 8, 2), 256, 0, stream>>>(
        cat + 2 * C0S, CAT, 512, cv1_c, 512, nullptr, 512, 0,
        cat, nullptr, CAT, nullptr, nullptr, nullptr, nullptr);
    // m0_cv1: b (cat ch 256..511) -> tmp
    k_mconv<9, false><<<dim3(32, 8, 1), 256, 0, stream>>>(
        cat + C0S, CAT, 256, wt9_0, 256, nullptr, 256, 0,
        tmp, nullptr, C0S, nullptr, nullptr, nullptr, nullptr);
    // m0_cv2: tmp -> b1 (cat ch 512..767; x region now dead)
    k_mconv<9, false><<<dim3(32, 8, 1), 256, 0, stream>>>(
        tmp, C0S, 256, wt9_1, 256, nullptr, 256, 0,
        cat + 2 * C0S, nullptr, CAT, nullptr, nullptr, nullptr, nullptr);
    // m1_cv1: b1 -> tmp
    k_mconv<9, false><<<dim3(32, 8, 1), 256, 0, stream>>>(
        cat + 2 * C0S, CAT, 256, wt9_2, 256, nullptr, 256, 0,
        tmp, nullptr, C0S, nullptr, nullptr, nullptr, nullptr);
    // m1_cv2: tmp -> b2 (cat ch 768..1023)
    k_mconv<9, false><<<dim3(32, 8, 1), 256, 0, stream>>>(
        tmp, C0S, 256, wt9_3, 256, nullptr, 256, 0,
        cat + 3 * C0S, nullptr, CAT, nullptr, nullptr, nullptr, nullptr);
    // qkv: b2 -> val / offb / awb  (352 real cols, padded to 384)
    k_mconv<1, false><<<dim3(32, 8, 2), 256, 0, stream>>>(
        cat + 3 * C0S, CAT, 256, wTq, 384, qb, 384, 2,
        nullptr, nullptr, 0, nullptr, val, offb, awb);
    // sampler (tmp dead -> sout reuses U+0)
    k_samp<<<dim3(32768), 256, 0, stream>>>(d_in[1], flag, offb, awb, val, sout);
    // outproj: sout (px-major) -> cat ch 1024..1279, +bias, no act
    k_mconv<1, true><<<dim3(32, 8, 1), 256, 0, stream>>>(
        sout, (long)L_N * 256, 256, wTo, 256, outb_c, 256, 3,
        cat + 4 * C0S, nullptr, CAT, nullptr, nullptr, nullptr, nullptr);
    // cv2: cat (1280ch) -> out (512ch), silu, dtype per flag
    k_mconv<1, false><<<dim3(32, 8, 2), 256, 0, stream>>>(
        cat, CAT, 1280, cv2_c, 512, nullptr, 512, 1,
        (BF*)d_out, (float*)d_out, C1S, flag, nullptr, nullptr, nullptr);
}